// Round 5
// baseline (355.347 us; speedup 1.0000x reference)
//
#include <hip/hip_runtime.h>
#include <hip/hip_bf16.h>

typedef __attribute__((ext_vector_type(8))) short short8;
typedef __attribute__((ext_vector_type(4))) short shortx4;
typedef __attribute__((ext_vector_type(4))) float floatx4;
typedef __attribute__((ext_vector_type(4))) unsigned int uintx4;

#define BB 8
#define TT 4096
#define CC 1024
#define HH 128
#define BT (BB * TT)

__device__ __forceinline__ unsigned short f2bf(float f) {
    unsigned int u = __float_as_uint(f);
    u += 0x7fffu + ((u >> 16) & 1u);   // round-to-nearest-even
    return (unsigned short)(u >> 16);
}

// async global->LDS, 16B per lane; lds dest = wave-uniform base + lane*16
__device__ __forceinline__ void async16(const unsigned short* g, unsigned short* l) {
    __builtin_amdgcn_global_load_lds(
        (const __attribute__((address_space(1))) unsigned int*)g,
        (__attribute__((address_space(3))) unsigned int*)l, 16, 0, 0);
}

// ---------------- W [C][H] fp32 (x3) -> Wt [3*H][C] bf16 transposed ----------------
__global__ void conv_w(const float* __restrict__ Wq, const float* __restrict__ Wk,
                       const float* __restrict__ Wv, unsigned short* __restrict__ Wt) {
    __shared__ float tile[32][33];
    const int w = blockIdx.z, nt = blockIdx.y, kt = blockIdx.x;
    const int tx = threadIdx.x, ty = threadIdx.y;  // 32 x 8
    const float* W = (w == 0) ? Wq : ((w == 1) ? Wk : Wv);
#pragma unroll
    for (int i = 0; i < 4; ++i)
        tile[ty + 8 * i][tx] = W[(kt * 32 + ty + 8 * i) * HH + nt * 32 + tx];
    __syncthreads();
#pragma unroll
    for (int i = 0; i < 4; ++i)
        Wt[w * (HH * CC) + (nt * 32 + ty + 8 * i) * CC + kt * 32 + tx] = f2bf(tile[tx][ty + 8 * i]);
}

// ---------------- fused single-pass QKV projection ----------------
// grid 512 (M/64); block 256 = 4 waves; wave w owns n-frags [6w,6w+6), all 4 m-frags
__global__ __launch_bounds__(256) void proj_gemm(
    const float* __restrict__ x, const unsigned short* __restrict__ Wt,
    const float* __restrict__ bq, const float* __restrict__ bk, const float* __restrict__ bv,
    unsigned short* __restrict__ Qb, unsigned short* __restrict__ Kb,
    unsigned short* __restrict__ Vt) {
    __shared__ unsigned short As[64 * 72];    // padded
    __shared__ unsigned short Bs[384 * 64];   // swizzled: slot(row,sc) holds global chunk sc^(row&7)
    const int mbase = blockIdx.x * 64;
    const int tid = threadIdx.x, lane = tid & 63, wv = tid >> 6;
    const int quad = lane >> 4, l15 = lane & 15;
    const int arow = tid >> 2, aseg = tid & 3;
    const int brow = lane >> 3;                       // staging row-within-group
    const int wc = (lane & 7) ^ (brow & 7);           // swizzled global chunk (loop-invariant)

    floatx4 acc[4][6];
#pragma unroll
    for (int i = 0; i < 4; ++i)
#pragma unroll
        for (int j = 0; j < 6; ++j) {
            floatx4 z = {0.f, 0.f, 0.f, 0.f};
            acc[i][j] = z;
        }

    for (int kt = 0; kt < 16; ++kt) {
        {   // A: 64x64 fp32 -> bf16 into LDS
            const float* xp = x + (long)(mbase + arow) * CC + kt * 64 + aseg * 16;
            floatx4 f0 = *(const floatx4*)(xp);
            floatx4 f1 = *(const floatx4*)(xp + 4);
            floatx4 f2 = *(const floatx4*)(xp + 8);
            floatx4 f3 = *(const floatx4*)(xp + 12);
            uintx4 p0, p1;
            p0[0] = (unsigned)f2bf(f0[0]) | ((unsigned)f2bf(f0[1]) << 16);
            p0[1] = (unsigned)f2bf(f0[2]) | ((unsigned)f2bf(f0[3]) << 16);
            p0[2] = (unsigned)f2bf(f1[0]) | ((unsigned)f2bf(f1[1]) << 16);
            p0[3] = (unsigned)f2bf(f1[2]) | ((unsigned)f2bf(f1[3]) << 16);
            p1[0] = (unsigned)f2bf(f2[0]) | ((unsigned)f2bf(f2[1]) << 16);
            p1[1] = (unsigned)f2bf(f2[2]) | ((unsigned)f2bf(f2[3]) << 16);
            p1[2] = (unsigned)f2bf(f3[0]) | ((unsigned)f2bf(f3[1]) << 16);
            p1[3] = (unsigned)f2bf(f3[2]) | ((unsigned)f2bf(f3[3]) << 16);
            *(uintx4*)&As[arow * 72 + aseg * 16] = p0;
            *(uintx4*)&As[arow * 72 + aseg * 16 + 8] = p1;
        }
#pragma unroll
        for (int h = 0; h < 12; ++h) {  // B: 384x64 via async, swizzled
            int grp = 4 * h + wv;
            async16(Wt + (long)(grp * 8 + brow) * CC + kt * 64 + wc * 8, &Bs[grp * 512]);
        }
        __syncthreads();
#pragma unroll
        for (int ks = 0; ks < 2; ++ks) {
            short8 af[4];
#pragma unroll
            for (int mi = 0; mi < 4; ++mi)
                af[mi] = *(const short8*)&As[(mi * 16 + l15) * 72 + ks * 32 + quad * 8];
#pragma unroll
            for (int ni = 0; ni < 6; ++ni) {
                short8 bfr = *(const short8*)&Bs[(wv * 96 + ni * 16 + l15) * 64 +
                                                 (((ks * 4 + quad) ^ (l15 & 7)) * 8)];
#pragma unroll
                for (int mi = 0; mi < 4; ++mi)
                    acc[mi][ni] = __builtin_amdgcn_mfma_f32_16x16x32_bf16(af[mi], bfr, acc[mi][ni], 0, 0, 0);
            }
        }
        __syncthreads();
    }

    // epilogue: f = wv*6+ni: f<8 -> Q (pre-scaled by scale*log2e), f<16 -> K, else V (LDS transpose)
    const float qscale = 0.08838834764831845f * 1.4426950408889634f;
    unsigned short* Tw = &As[wv * 1152];  // 16h x 72 per wave for V transpose
#pragma unroll
    for (int ni = 0; ni < 6; ++ni) {
        int f = wv * 6 + ni;
        int col = f * 16 + l15;
        int h = col & 127;
        if (f < 16) {
            float bval = (f < 8) ? bq[h] : bk[h];
            unsigned short* dst = (f < 8) ? Qb : Kb;
#pragma unroll
            for (int mi = 0; mi < 4; ++mi)
#pragma unroll
                for (int r = 0; r < 4; ++r) {
                    int row = mbase + mi * 16 + quad * 4 + r;
                    float v = acc[mi][ni][r] + bval;
                    if (f < 8) v *= qscale;
                    dst[(long)row * HH + h] = f2bf(v);
                }
        } else {
            float bval = bv[h];
            // write [h=l15][t] tile to LDS, 4 t's packed per store
#pragma unroll
            for (int mi = 0; mi < 4; ++mi) {
                shortx4 pk;
#pragma unroll
                for (int r = 0; r < 4; ++r) pk[r] = (short)f2bf(acc[mi][ni][r] + bval);
                *(shortx4*)&Tw[l15 * 72 + mi * 16 + quad * 4] = pk;
            }
            // wave-local read + coalesced store: lane covers (h=lane>>2, 16 t's)
            int th = lane >> 2, seg = lane & 3;
            uintx4 q0 = *(const uintx4*)&Tw[th * 72 + seg * 16];
            uintx4 q1 = *(const uintx4*)&Tw[th * 72 + seg * 16 + 8];
            int hg = (f - 16) * 16 + th;
            int bb = mbase >> 12, t0 = (mbase & 4095) + seg * 16;
            unsigned short* vp = Vt + (long)bb * (HH * TT) + (long)hg * TT + t0;
            *(uintx4*)(vp) = q0;
            *(uintx4*)(vp + 8) = q1;
        }
    }
}

// ---------------- flash attention, causal, split-KV S=2, async-staged, swizzled LDS ----------------
// grid 1024 = 64 qb (descending) x 8 b x 2 s; block 256 (4 waves x 16 q-rows); 37,888 B LDS -> 4 blocks/CU
__global__ __launch_bounds__(256) void attn(
    const unsigned short* __restrict__ Qb, const unsigned short* __restrict__ Kb,
    const unsigned short* __restrict__ Vt, unsigned short* __restrict__ Op0,
    unsigned short* __restrict__ Op1, float2* __restrict__ Ml) {
    __shared__ unsigned short Ks[64 * 128];   // swizzled: slot(r,sc) holds chunk sc^(r&15)
    __shared__ unsigned short Vs[128 * 64];   // swizzled: slot(h,sc) holds chunk sc^(h&7)
    __shared__ unsigned short Ps[4 * 16 * 40];
    const int gid = blockIdx.x;
    const int qb = 63 - (gid >> 4);
    const int sub = gid & 15;
    const int b = sub & 7;
    const int s = sub >> 3;
    const int mid = (qb + 1) >> 1;
    const int lo = (s == 0) ? 0 : mid;
    const int hi = (s == 0) ? mid : qb + 1;
    const int tid = threadIdx.x, lane = tid & 63, wv = tid >> 6;
    const int quad = lane >> 4, l15 = lane & 15;

    short8 qf[4];
    {
        const unsigned short* qp = Qb + ((long)b * TT + qb * 64 + wv * 16 + l15) * HH + quad * 8;
#pragma unroll
        for (int ks = 0; ks < 4; ++ks) qf[ks] = *(const short8*)(qp + ks * 32);
    }
    floatx4 o[8];
#pragma unroll
    for (int i = 0; i < 8; ++i) {
        floatx4 z = {0.f, 0.f, 0.f, 0.f};
        o[i] = z;
    }
    float m_r[4] = {-1e30f, -1e30f, -1e30f, -1e30f};
    float l_r[4] = {0.f, 0.f, 0.f, 0.f};

    // staging addresses (loop-invariant components)
    const int kc = l15 ^ (4 * wv + quad);
    const unsigned short* Kg = Kb + (long)b * TT * HH + ((long)lo * 64 + 4 * wv + quad) * HH + kc * 8;
    const int vrow = lane >> 3;
    const int vc = (lane & 7) ^ (vrow & 7);
    const unsigned short* Vg = Vt + (long)b * HH * TT + (long)(8 * wv + vrow) * TT + lo * 64 + vc * 8;
    unsigned short* Pw = &Ps[wv * 640];

    for (int kb = lo; kb < hi; ++kb) {
#pragma unroll
        for (int h = 0; h < 4; ++h) {
            int grp = 4 * h + wv;
            async16(Kg + (long)h * (16 * HH), &Ks[grp * 512]);
            async16(Vg + (long)h * 32 * TT, &Vs[grp * 512]);
        }
        Kg += (long)64 * HH;
        Vg += 64;
        __syncthreads();

        floatx4 sArr[4];
#pragma unroll
        for (int nt = 0; nt < 4; ++nt) {
            floatx4 z = {0.f, 0.f, 0.f, 0.f};
            sArr[nt] = z;
        }
#pragma unroll
        for (int ks = 0; ks < 4; ++ks)
#pragma unroll
            for (int nt = 0; nt < 4; ++nt) {
                short8 kf = *(const short8*)&Ks[(nt * 16 + l15) * 128 + (((ks * 4 + quad) ^ l15) * 8)];
                sArr[nt] = __builtin_amdgcn_mfma_f32_16x16x32_bf16(qf[ks], kf, sArr[nt], 0, 0, 0);
            }

        if (kb == qb) {  // diagonal causal mask
            int rowl = wv * 16 + quad * 4;
#pragma unroll
            for (int nt = 0; nt < 4; ++nt) {
                int col = nt * 16 + l15;
#pragma unroll
                for (int r = 0; r < 4; ++r)
                    if (col > rowl + r) sArr[nt][r] = -1e30f;
            }
        }

        float alpha[4];
#pragma unroll
        for (int r = 0; r < 4; ++r) {
            float mx = fmaxf(fmaxf(sArr[0][r], sArr[1][r]), fmaxf(sArr[2][r], sArr[3][r]));
#pragma unroll
            for (int off = 1; off < 16; off <<= 1) mx = fmaxf(mx, __shfl_xor(mx, off));
            float mnew = fmaxf(m_r[r], mx);
            alpha[r] = exp2f(m_r[r] - mnew);   // log2-domain (Q pre-scaled by scale*log2e)
            m_r[r] = mnew;
            float rs = 0.f;
#pragma unroll
            for (int nt = 0; nt < 4; ++nt) {
                float p = exp2f(sArr[nt][r] - mnew);
                sArr[nt][r] = p;
                rs += p;
            }
#pragma unroll
            for (int off = 1; off < 16; off <<= 1) rs += __shfl_xor(rs, off);
            l_r[r] = l_r[r] * alpha[r] + rs;
        }
#pragma unroll
        for (int hn = 0; hn < 8; ++hn)
#pragma unroll
            for (int r = 0; r < 4; ++r) o[hn][r] *= alpha[r];

        // PV in two k2 halves through per-wave LDS (C-layout -> A-layout)
#pragma unroll
        for (int k2 = 0; k2 < 2; ++k2) {
#pragma unroll
            for (int ntl = 0; ntl < 2; ++ntl)
#pragma unroll
                for (int r = 0; r < 4; ++r)
                    Pw[(quad * 4 + r) * 40 + ntl * 16 + l15] = f2bf(sArr[k2 * 2 + ntl][r]);
            short8 pf = *(const short8*)&Pw[l15 * 40 + quad * 8];
#pragma unroll
            for (int hn = 0; hn < 8; ++hn) {
                short8 vf = *(const short8*)&Vs[(hn * 16 + l15) * 64 +
                                                (((k2 * 4 + quad) ^ (l15 & 7)) * 8)];
                o[hn] = __builtin_amdgcn_mfma_f32_16x16x32_bf16(pf, vf, o[hn], 0, 0, 0);
            }
        }
        __syncthreads();
    }

    unsigned short* Op = (s == 0) ? Op0 : Op1;
    long rbase = (long)b * TT + qb * 64 + wv * 16 + quad * 4;
    if (hi > lo) {
#pragma unroll
        for (int hn = 0; hn < 8; ++hn)
#pragma unroll
            for (int r = 0; r < 4; ++r)
                Op[(rbase + r) * HH + hn * 16 + l15] = f2bf(o[hn][r] / l_r[r]);
    }
    if (l15 == 0) {
#pragma unroll
        for (int r = 0; r < 4; ++r) {
            float2 ml;
            ml.x = m_r[r];
            ml.y = l_r[r];
            Ml[(long)s * BT + rbase + r] = ml;
        }
    }
}

// ---------------- merge the two KV-chunk partials (log2 domain) ----------------
__global__ __launch_bounds__(256) void merge_kern(
    const unsigned short* __restrict__ Op0, const unsigned short* __restrict__ Op1,
    const float2* __restrict__ Ml, float* __restrict__ out) {
    long e = ((long)blockIdx.x * 256 + threadIdx.x) * 8;
    long row = e >> 7;
    float2 a = Ml[row];
    float2 c = Ml[BT + row];
    float ms = fmaxf(a.x, c.x);
    float w0 = a.y * exp2f(a.x - ms);
    float w1 = c.y * exp2f(c.x - ms);
    float inv = 1.f / (w0 + w1);
    w0 *= inv;
    w1 *= inv;
    uintx4 p0 = *(const uintx4*)(Op0 + e);
    uintx4 p1 = *(const uintx4*)(Op1 + e);
    floatx4 o0, o1;
#pragma unroll
    for (int j = 0; j < 4; ++j) {
        float a0 = __uint_as_float(p0[j] << 16);
        float a1 = __uint_as_float(p0[j] & 0xffff0000u);
        float b0 = __uint_as_float(p1[j] << 16);
        float b1 = __uint_as_float(p1[j] & 0xffff0000u);
        if (j < 2) {
            o0[2 * j] = w0 * a0 + w1 * b0;
            o0[2 * j + 1] = w0 * a1 + w1 * b1;
        } else {
            o1[2 * (j - 2)] = w0 * a0 + w1 * b0;
            o1[2 * (j - 2) + 1] = w0 * a1 + w1 * b1;
        }
    }
    *(floatx4*)(out + e) = o0;
    *(floatx4*)(out + e + 4) = o1;
}

extern "C" void kernel_launch(void* const* d_in, const int* in_sizes, int n_in,
                              void* d_out, int out_size, void* d_ws, size_t ws_size,
                              hipStream_t stream) {
    const float* x  = (const float*)d_in[0];
    const float* Wq = (const float*)d_in[1];
    const float* bq = (const float*)d_in[2];
    const float* Wk = (const float*)d_in[3];
    const float* bk = (const float*)d_in[4];
    const float* Wv = (const float*)d_in[5];
    const float* bv = (const float*)d_in[6];
    float* out = (float*)d_out;

    char* ws = (char*)d_ws;
    unsigned short* Wt  = (unsigned short*)(ws);              // 786,432 B
    unsigned short* Qb  = (unsigned short*)(ws + 1048576);    // pre-scaled by scale*log2e
    unsigned short* Kb  = (unsigned short*)(ws + 9437184);
    unsigned short* Vt  = (unsigned short*)(ws + 17825792);   // [B][H][T]
    unsigned short* Op0 = (unsigned short*)(ws + 26214400);
    unsigned short* Op1 = (unsigned short*)(ws + 34603008);
    float2*         Ml  = (float2*)(ws + 42991616);
    // total ws use: 43,515,904 bytes

    conv_w<<<dim3(32, 4, 3), dim3(32, 8), 0, stream>>>(Wq, Wk, Wv, Wt);
    proj_gemm<<<512, 256, 0, stream>>>(x, Wt, bq, bk, bv, Qb, Kb, Vt);
    attn<<<1024, 256, 0, stream>>>(Qb, Kb, Vt, Op0, Op1, Ml);
    merge_kern<<<2048, 256, 0, stream>>>(Op0, Op1, Ml, out);
}

// Round 6
// 331.154 us; speedup vs baseline: 1.0731x; 1.0731x over previous
//
#include <hip/hip_runtime.h>
#include <hip/hip_bf16.h>

typedef __attribute__((ext_vector_type(8))) short short8;
typedef __attribute__((ext_vector_type(4))) short shortx4;
typedef __attribute__((ext_vector_type(4))) float floatx4;
typedef __attribute__((ext_vector_type(4))) unsigned int uintx4;

#define BB 8
#define TT 4096
#define CC 1024
#define HH 128
#define BT (BB * TT)

__device__ __forceinline__ unsigned short f2bf(float f) {
    unsigned int u = __float_as_uint(f);
    u += 0x7fffu + ((u >> 16) & 1u);   // round-to-nearest-even
    return (unsigned short)(u >> 16);
}

// async global->LDS, 16B per lane; lds dest = wave-uniform base + lane*16
__device__ __forceinline__ void async16(const unsigned short* g, unsigned short* l) {
    __builtin_amdgcn_global_load_lds(
        (const __attribute__((address_space(1))) unsigned int*)g,
        (__attribute__((address_space(3))) unsigned int*)l, 16, 0, 0);
}

// ---------------- W [C][H] fp32 (x3) -> Wt [3*H][C] bf16 transposed ----------------
__global__ void conv_w(const float* __restrict__ Wq, const float* __restrict__ Wk,
                       const float* __restrict__ Wv, unsigned short* __restrict__ Wt) {
    __shared__ float tile[32][33];
    const int w = blockIdx.z, nt = blockIdx.y, kt = blockIdx.x;
    const int tx = threadIdx.x, ty = threadIdx.y;  // 32 x 8
    const float* W = (w == 0) ? Wq : ((w == 1) ? Wk : Wv);
#pragma unroll
    for (int i = 0; i < 4; ++i)
        tile[ty + 8 * i][tx] = W[(kt * 32 + ty + 8 * i) * HH + nt * 32 + tx];
    __syncthreads();
#pragma unroll
    for (int i = 0; i < 4; ++i)
        Wt[w * (HH * CC) + (nt * 32 + ty + 8 * i) * CC + kt * 32 + tx] = f2bf(tile[tx][ty + 8 * i]);
}

// ---------------- fused single-pass QKV projection, N-split ----------------
// grid (2, 512): nb = N-half, mb = M/64; block 256 = 4 waves; wave owns 3 n-frags x 4 m-frags
// LDS 33,792 B -> 4 blocks/CU; grid 1024 -> 4 resident blocks/CU (16 waves)
__global__ __launch_bounds__(256, 4) void proj_gemm(
    const float* __restrict__ x, const unsigned short* __restrict__ Wt,
    const float* __restrict__ bq, const float* __restrict__ bk, const float* __restrict__ bv,
    unsigned short* __restrict__ Qb, unsigned short* __restrict__ Kb,
    unsigned short* __restrict__ Vt) {
    __shared__ unsigned short As[64 * 72];    // padded
    __shared__ unsigned short Bs[192 * 64];   // swizzled: slot(row,sc) holds global chunk sc^(row&7)
    const int nb = blockIdx.x;                // 0 or 1: frags [12nb, 12nb+12)
    const int mbase = blockIdx.y * 64;
    const int tid = threadIdx.x, lane = tid & 63, wv = tid >> 6;
    const int quad = lane >> 4, l15 = lane & 15;
    const int arow = tid >> 2, aseg = tid & 3;
    const int brow = lane >> 3;                       // staging row-within-group
    const int wc = (lane & 7) ^ (brow & 7);           // swizzled global chunk (loop-invariant)
    const unsigned short* Wp = Wt + (long)nb * 192 * CC;

    floatx4 acc[4][3];
#pragma unroll
    for (int i = 0; i < 4; ++i)
#pragma unroll
        for (int j = 0; j < 3; ++j) {
            floatx4 z = {0.f, 0.f, 0.f, 0.f};
            acc[i][j] = z;
        }

    for (int kt = 0; kt < 16; ++kt) {
        {   // A: 64x64 fp32 -> bf16 into LDS
            const float* xp = x + (long)(mbase + arow) * CC + kt * 64 + aseg * 16;
            floatx4 f0 = *(const floatx4*)(xp);
            floatx4 f1 = *(const floatx4*)(xp + 4);
            floatx4 f2 = *(const floatx4*)(xp + 8);
            floatx4 f3 = *(const floatx4*)(xp + 12);
            uintx4 p0, p1;
            p0[0] = (unsigned)f2bf(f0[0]) | ((unsigned)f2bf(f0[1]) << 16);
            p0[1] = (unsigned)f2bf(f0[2]) | ((unsigned)f2bf(f0[3]) << 16);
            p0[2] = (unsigned)f2bf(f1[0]) | ((unsigned)f2bf(f1[1]) << 16);
            p0[3] = (unsigned)f2bf(f1[2]) | ((unsigned)f2bf(f1[3]) << 16);
            p1[0] = (unsigned)f2bf(f2[0]) | ((unsigned)f2bf(f2[1]) << 16);
            p1[1] = (unsigned)f2bf(f2[2]) | ((unsigned)f2bf(f2[3]) << 16);
            p1[2] = (unsigned)f2bf(f3[0]) | ((unsigned)f2bf(f3[1]) << 16);
            p1[3] = (unsigned)f2bf(f3[2]) | ((unsigned)f2bf(f3[3]) << 16);
            *(uintx4*)&As[arow * 72 + aseg * 16] = p0;
            *(uintx4*)&As[arow * 72 + aseg * 16 + 8] = p1;
        }
#pragma unroll
        for (int h = 0; h < 6; ++h) {  // B: 192x64 via async, swizzled
            int grp = 4 * h + wv;      // 0..23
            async16(Wp + (long)(grp * 8 + brow) * CC + kt * 64 + wc * 8, &Bs[grp * 512]);
        }
        __syncthreads();
#pragma unroll
        for (int ks = 0; ks < 2; ++ks) {
            short8 af[4];
#pragma unroll
            for (int mi = 0; mi < 4; ++mi)
                af[mi] = *(const short8*)&As[(mi * 16 + l15) * 72 + ks * 32 + quad * 8];
#pragma unroll
            for (int ni = 0; ni < 3; ++ni) {
                short8 bfr = *(const short8*)&Bs[((wv * 3 + ni) * 16 + l15) * 64 +
                                                 (((ks * 4 + quad) ^ (l15 & 7)) * 8)];
#pragma unroll
                for (int mi = 0; mi < 4; ++mi)
                    acc[mi][ni] = __builtin_amdgcn_mfma_f32_16x16x32_bf16(af[mi], bfr, acc[mi][ni], 0, 0, 0);
            }
        }
        __syncthreads();
    }

    // epilogue: f = 12nb + 3wv + ni: f<8 -> Q (pre-scaled by scale*log2e), f<16 -> K, else V (LDS transpose)
    const float qscale = 0.08838834764831845f * 1.4426950408889634f;
    unsigned short* Tw = &As[wv * 1152];  // 16h x 72 per wave for V transpose
#pragma unroll
    for (int ni = 0; ni < 3; ++ni) {
        int f = 12 * nb + 3 * wv + ni;
        int col = f * 16 + l15;
        int h = col & 127;
        if (f < 16) {
            float bval = (f < 8) ? bq[h] : bk[h];
            unsigned short* dst = (f < 8) ? Qb : Kb;
#pragma unroll
            for (int mi = 0; mi < 4; ++mi)
#pragma unroll
                for (int r = 0; r < 4; ++r) {
                    int row = mbase + mi * 16 + quad * 4 + r;
                    float v = acc[mi][ni][r] + bval;
                    if (f < 8) v *= qscale;
                    dst[(long)row * HH + h] = f2bf(v);
                }
        } else {
            float bval = bv[h];
            // write [h=l15][t] tile to LDS, 4 t's packed per store
#pragma unroll
            for (int mi = 0; mi < 4; ++mi) {
                shortx4 pk;
#pragma unroll
                for (int r = 0; r < 4; ++r) pk[r] = (short)f2bf(acc[mi][ni][r] + bval);
                *(shortx4*)&Tw[l15 * 72 + mi * 16 + quad * 4] = pk;
            }
            // wave-local read + coalesced store: lane covers (h=lane>>2, 16 t's)
            int th = lane >> 2, seg = lane & 3;
            uintx4 q0 = *(const uintx4*)&Tw[th * 72 + seg * 16];
            uintx4 q1 = *(const uintx4*)&Tw[th * 72 + seg * 16 + 8];
            int hg = (f - 16) * 16 + th;
            int bb = mbase >> 12, t0 = (mbase & 4095) + seg * 16;
            unsigned short* vp = Vt + (long)bb * (HH * TT) + (long)hg * TT + t0;
            *(uintx4*)(vp) = q0;
            *(uintx4*)(vp + 8) = q1;
        }
    }
}

// ---------------- flash attention, causal, split-KV S=2, async-staged, swizzled LDS ----------------
// grid 1024 = 64 qb (descending) x 8 b x 2 s; block 256 (4 waves x 16 q-rows); 37,888 B LDS -> 4 blocks/CU
__global__ __launch_bounds__(256) void attn(
    const unsigned short* __restrict__ Qb, const unsigned short* __restrict__ Kb,
    const unsigned short* __restrict__ Vt, unsigned short* __restrict__ Op0,
    unsigned short* __restrict__ Op1, float2* __restrict__ Ml) {
    __shared__ unsigned short Ks[64 * 128];   // swizzled: slot(r,sc) holds chunk sc^(r&15)
    __shared__ unsigned short Vs[128 * 64];   // swizzled: slot(h,sc) holds chunk sc^(h&7)
    __shared__ unsigned short Ps[4 * 16 * 40];
    const int gid = blockIdx.x;
    const int qb = 63 - (gid >> 4);
    const int sub = gid & 15;
    const int b = sub & 7;
    const int s = sub >> 3;
    const int mid = (qb + 1) >> 1;
    const int lo = (s == 0) ? 0 : mid;
    const int hi = (s == 0) ? mid : qb + 1;
    const int tid = threadIdx.x, lane = tid & 63, wv = tid >> 6;
    const int quad = lane >> 4, l15 = lane & 15;

    short8 qf[4];
    {
        const unsigned short* qp = Qb + ((long)b * TT + qb * 64 + wv * 16 + l15) * HH + quad * 8;
#pragma unroll
        for (int ks = 0; ks < 4; ++ks) qf[ks] = *(const short8*)(qp + ks * 32);
    }
    floatx4 o[8];
#pragma unroll
    for (int i = 0; i < 8; ++i) {
        floatx4 z = {0.f, 0.f, 0.f, 0.f};
        o[i] = z;
    }
    float m_r[4] = {-1e30f, -1e30f, -1e30f, -1e30f};
    float l_r[4] = {0.f, 0.f, 0.f, 0.f};

    // staging addresses (loop-invariant components)
    const int kc = l15 ^ (4 * wv + quad);
    const unsigned short* Kg = Kb + (long)b * TT * HH + ((long)lo * 64 + 4 * wv + quad) * HH + kc * 8;
    const int vrow = lane >> 3;
    const int vc = (lane & 7) ^ (vrow & 7);
    const unsigned short* Vg = Vt + (long)b * HH * TT + (long)(8 * wv + vrow) * TT + lo * 64 + vc * 8;
    unsigned short* Pw = &Ps[wv * 640];

    for (int kb = lo; kb < hi; ++kb) {
#pragma unroll
        for (int h = 0; h < 4; ++h) {
            int grp = 4 * h + wv;
            async16(Kg + (long)h * (16 * HH), &Ks[grp * 512]);
            async16(Vg + (long)h * 32 * TT, &Vs[grp * 512]);
        }
        Kg += (long)64 * HH;
        Vg += 64;
        __syncthreads();

        floatx4 sArr[4];
#pragma unroll
        for (int nt = 0; nt < 4; ++nt) {
            floatx4 z = {0.f, 0.f, 0.f, 0.f};
            sArr[nt] = z;
        }
#pragma unroll
        for (int ks = 0; ks < 4; ++ks)
#pragma unroll
            for (int nt = 0; nt < 4; ++nt) {
                short8 kf = *(const short8*)&Ks[(nt * 16 + l15) * 128 + (((ks * 4 + quad) ^ l15) * 8)];
                sArr[nt] = __builtin_amdgcn_mfma_f32_16x16x32_bf16(qf[ks], kf, sArr[nt], 0, 0, 0);
            }

        if (kb == qb) {  // diagonal causal mask
            int rowl = wv * 16 + quad * 4;
#pragma unroll
            for (int nt = 0; nt < 4; ++nt) {
                int col = nt * 16 + l15;
#pragma unroll
                for (int r = 0; r < 4; ++r)
                    if (col > rowl + r) sArr[nt][r] = -1e30f;
            }
        }

        float alpha[4];
#pragma unroll
        for (int r = 0; r < 4; ++r) {
            float mx = fmaxf(fmaxf(sArr[0][r], sArr[1][r]), fmaxf(sArr[2][r], sArr[3][r]));
#pragma unroll
            for (int off = 1; off < 16; off <<= 1) mx = fmaxf(mx, __shfl_xor(mx, off));
            float mnew = fmaxf(m_r[r], mx);
            alpha[r] = exp2f(m_r[r] - mnew);   // log2-domain (Q pre-scaled by scale*log2e)
            m_r[r] = mnew;
            float rs = 0.f;
#pragma unroll
            for (int nt = 0; nt < 4; ++nt) {
                float p = exp2f(sArr[nt][r] - mnew);
                sArr[nt][r] = p;
                rs += p;
            }
#pragma unroll
            for (int off = 1; off < 16; off <<= 1) rs += __shfl_xor(rs, off);
            l_r[r] = l_r[r] * alpha[r] + rs;
        }
#pragma unroll
        for (int hn = 0; hn < 8; ++hn)
#pragma unroll
            for (int r = 0; r < 4; ++r) o[hn][r] *= alpha[r];

        // PV in two k2 halves through per-wave LDS (C-layout -> A-layout)
#pragma unroll
        for (int k2 = 0; k2 < 2; ++k2) {
#pragma unroll
            for (int ntl = 0; ntl < 2; ++ntl)
#pragma unroll
                for (int r = 0; r < 4; ++r)
                    Pw[(quad * 4 + r) * 40 + ntl * 16 + l15] = f2bf(sArr[k2 * 2 + ntl][r]);
            short8 pf = *(const short8*)&Pw[l15 * 40 + quad * 8];
#pragma unroll
            for (int hn = 0; hn < 8; ++hn) {
                short8 vf = *(const short8*)&Vs[(hn * 16 + l15) * 64 +
                                                (((k2 * 4 + quad) ^ (l15 & 7)) * 8)];
                o[hn] = __builtin_amdgcn_mfma_f32_16x16x32_bf16(pf, vf, o[hn], 0, 0, 0);
            }
        }
        __syncthreads();
    }

    unsigned short* Op = (s == 0) ? Op0 : Op1;
    long rbase = (long)b * TT + qb * 64 + wv * 16 + quad * 4;
    if (hi > lo) {
#pragma unroll
        for (int hn = 0; hn < 8; ++hn)
#pragma unroll
            for (int r = 0; r < 4; ++r)
                Op[(rbase + r) * HH + hn * 16 + l15] = f2bf(o[hn][r] / l_r[r]);
    }
    if (l15 == 0) {
#pragma unroll
        for (int r = 0; r < 4; ++r) {
            float2 ml;
            ml.x = m_r[r];
            ml.y = l_r[r];
            Ml[(long)s * BT + rbase + r] = ml;
        }
    }
}

// ---------------- merge the two KV-chunk partials (log2 domain) ----------------
__global__ __launch_bounds__(256) void merge_kern(
    const unsigned short* __restrict__ Op0, const unsigned short* __restrict__ Op1,
    const float2* __restrict__ Ml, float* __restrict__ out) {
    long e = ((long)blockIdx.x * 256 + threadIdx.x) * 8;
    long row = e >> 7;
    float2 a = Ml[row];
    float2 c = Ml[BT + row];
    float ms = fmaxf(a.x, c.x);
    float w0 = a.y * exp2f(a.x - ms);
    float w1 = c.y * exp2f(c.x - ms);
    float inv = 1.f / (w0 + w1);
    w0 *= inv;
    w1 *= inv;
    uintx4 p0 = *(const uintx4*)(Op0 + e);
    uintx4 p1 = *(const uintx4*)(Op1 + e);
    floatx4 o0, o1;
#pragma unroll
    for (int j = 0; j < 4; ++j) {
        float a0 = __uint_as_float(p0[j] << 16);
        float a1 = __uint_as_float(p0[j] & 0xffff0000u);
        float b0 = __uint_as_float(p1[j] << 16);
        float b1 = __uint_as_float(p1[j] & 0xffff0000u);
        if (j < 2) {
            o0[2 * j] = w0 * a0 + w1 * b0;
            o0[2 * j + 1] = w0 * a1 + w1 * b1;
        } else {
            o1[2 * (j - 2)] = w0 * a0 + w1 * b0;
            o1[2 * (j - 2) + 1] = w0 * a1 + w1 * b1;
        }
    }
    *(floatx4*)(out + e) = o0;
    *(floatx4*)(out + e + 4) = o1;
}

extern "C" void kernel_launch(void* const* d_in, const int* in_sizes, int n_in,
                              void* d_out, int out_size, void* d_ws, size_t ws_size,
                              hipStream_t stream) {
    const float* x  = (const float*)d_in[0];
    const float* Wq = (const float*)d_in[1];
    const float* bq = (const float*)d_in[2];
    const float* Wk = (const float*)d_in[3];
    const float* bk = (const float*)d_in[4];
    const float* Wv = (const float*)d_in[5];
    const float* bv = (const float*)d_in[6];
    float* out = (float*)d_out;

    char* ws = (char*)d_ws;
    unsigned short* Wt  = (unsigned short*)(ws);              // 786,432 B
    unsigned short* Qb  = (unsigned short*)(ws + 1048576);    // pre-scaled by scale*log2e
    unsigned short* Kb  = (unsigned short*)(ws + 9437184);
    unsigned short* Vt  = (unsigned short*)(ws + 17825792);   // [B][H][T]
    unsigned short* Op0 = (unsigned short*)(ws + 26214400);
    unsigned short* Op1 = (unsigned short*)(ws + 34603008);
    float2*         Ml  = (float2*)(ws + 42991616);
    // total ws use: 43,515,904 bytes

    conv_w<<<dim3(32, 4, 3), dim3(32, 8), 0, stream>>>(Wq, Wk, Wv, Wt);
    proj_gemm<<<dim3(2, 512), 256, 0, stream>>>(x, Wt, bq, bk, bv, Qb, Kb, Vt);
    attn<<<1024, 256, 0, stream>>>(Qb, Kb, Vt, Op0, Op1, Ml);
    merge_kern<<<2048, 256, 0, stream>>>(Op0, Op1, Ml, out);
}

// Round 7
// 300.693 us; speedup vs baseline: 1.1818x; 1.1013x over previous
//
#include <hip/hip_runtime.h>
#include <hip/hip_bf16.h>

typedef __attribute__((ext_vector_type(8))) short short8;
typedef __attribute__((ext_vector_type(4))) short shortx4;
typedef __attribute__((ext_vector_type(4))) float floatx4;
typedef __attribute__((ext_vector_type(4))) unsigned int uintx4;

#define BB 8
#define TT 4096
#define CC 1024
#define HH 128
#define BT (BB * TT)
#define MBASE 16.0f

__device__ __forceinline__ unsigned short f2bf(float f) {
    unsigned int u = __float_as_uint(f);
    u += 0x7fffu + ((u >> 16) & 1u);   // round-to-nearest-even
    return (unsigned short)(u >> 16);
}

// async global->LDS, 16B per lane; lds dest = wave-uniform base + lane*16
__device__ __forceinline__ void async16(const unsigned short* g, unsigned short* l) {
    __builtin_amdgcn_global_load_lds(
        (const __attribute__((address_space(1))) unsigned int*)g,
        (__attribute__((address_space(3))) unsigned int*)l, 16, 0, 0);
}

// ---------------- W [C][H] fp32 (x3) -> Wt [3*H][C] bf16 transposed ----------------
__global__ void conv_w(const float* __restrict__ Wq, const float* __restrict__ Wk,
                       const float* __restrict__ Wv, unsigned short* __restrict__ Wt) {
    __shared__ float tile[32][33];
    const int w = blockIdx.z, nt = blockIdx.y, kt = blockIdx.x;
    const int tx = threadIdx.x, ty = threadIdx.y;  // 32 x 8
    const float* W = (w == 0) ? Wq : ((w == 1) ? Wk : Wv);
#pragma unroll
    for (int i = 0; i < 4; ++i)
        tile[ty + 8 * i][tx] = W[(kt * 32 + ty + 8 * i) * HH + nt * 32 + tx];
    __syncthreads();
#pragma unroll
    for (int i = 0; i < 4; ++i)
        Wt[w * (HH * CC) + (nt * 32 + ty + 8 * i) * CC + kt * 32 + tx] = f2bf(tile[tx][ty + 8 * i]);
}

// ---------------- fused single-pass QKV projection, N-split ----------------
// grid (2, 512): nb = N-half, mb = M/64; block 256 = 4 waves; wave owns 3 n-frags x 4 m-frags
__global__ __launch_bounds__(256, 4) void proj_gemm(
    const float* __restrict__ x, const unsigned short* __restrict__ Wt,
    const float* __restrict__ bq, const float* __restrict__ bk, const float* __restrict__ bv,
    unsigned short* __restrict__ Qb, unsigned short* __restrict__ Kb,
    unsigned short* __restrict__ Vt) {
    __shared__ unsigned short As[64 * 72];    // padded
    __shared__ unsigned short Bs[192 * 64];   // swizzled: slot(row,sc) holds global chunk sc^(row&7)
    const int nb = blockIdx.x;                // 0 or 1: frags [12nb, 12nb+12)
    const int mbase = blockIdx.y * 64;
    const int tid = threadIdx.x, lane = tid & 63, wv = tid >> 6;
    const int quad = lane >> 4, l15 = lane & 15;
    const int arow = tid >> 2, aseg = tid & 3;
    const int brow = lane >> 3;                       // staging row-within-group
    const int wc = (lane & 7) ^ (brow & 7);           // swizzled global chunk (loop-invariant)
    const unsigned short* Wp = Wt + (long)nb * 192 * CC;

    floatx4 acc[4][3];
#pragma unroll
    for (int i = 0; i < 4; ++i)
#pragma unroll
        for (int j = 0; j < 3; ++j) {
            floatx4 z = {0.f, 0.f, 0.f, 0.f};
            acc[i][j] = z;
        }

    for (int kt = 0; kt < 16; ++kt) {
        {   // A: 64x64 fp32 -> bf16 into LDS
            const float* xp = x + (long)(mbase + arow) * CC + kt * 64 + aseg * 16;
            floatx4 f0 = *(const floatx4*)(xp);
            floatx4 f1 = *(const floatx4*)(xp + 4);
            floatx4 f2 = *(const floatx4*)(xp + 8);
            floatx4 f3 = *(const floatx4*)(xp + 12);
            uintx4 p0, p1;
            p0[0] = (unsigned)f2bf(f0[0]) | ((unsigned)f2bf(f0[1]) << 16);
            p0[1] = (unsigned)f2bf(f0[2]) | ((unsigned)f2bf(f0[3]) << 16);
            p0[2] = (unsigned)f2bf(f1[0]) | ((unsigned)f2bf(f1[1]) << 16);
            p0[3] = (unsigned)f2bf(f1[2]) | ((unsigned)f2bf(f1[3]) << 16);
            p1[0] = (unsigned)f2bf(f2[0]) | ((unsigned)f2bf(f2[1]) << 16);
            p1[1] = (unsigned)f2bf(f2[2]) | ((unsigned)f2bf(f2[3]) << 16);
            p1[2] = (unsigned)f2bf(f3[0]) | ((unsigned)f2bf(f3[1]) << 16);
            p1[3] = (unsigned)f2bf(f3[2]) | ((unsigned)f2bf(f3[3]) << 16);
            *(uintx4*)&As[arow * 72 + aseg * 16] = p0;
            *(uintx4*)&As[arow * 72 + aseg * 16 + 8] = p1;
        }
#pragma unroll
        for (int h = 0; h < 6; ++h) {  // B: 192x64 via async, swizzled
            int grp = 4 * h + wv;      // 0..23
            async16(Wp + (long)(grp * 8 + brow) * CC + kt * 64 + wc * 8, &Bs[grp * 512]);
        }
        __syncthreads();
#pragma unroll
        for (int ks = 0; ks < 2; ++ks) {
            short8 af[4];
#pragma unroll
            for (int mi = 0; mi < 4; ++mi)
                af[mi] = *(const short8*)&As[(mi * 16 + l15) * 72 + ks * 32 + quad * 8];
#pragma unroll
            for (int ni = 0; ni < 3; ++ni) {
                short8 bfr = *(const short8*)&Bs[((wv * 3 + ni) * 16 + l15) * 64 +
                                                 (((ks * 4 + quad) ^ (l15 & 7)) * 8)];
#pragma unroll
                for (int mi = 0; mi < 4; ++mi)
                    acc[mi][ni] = __builtin_amdgcn_mfma_f32_16x16x32_bf16(af[mi], bfr, acc[mi][ni], 0, 0, 0);
            }
        }
        __syncthreads();
    }

    // epilogue: f = 12nb + 3wv + ni: f<8 -> Q (pre-scaled by scale*log2e), f<16 -> K, else V (LDS transpose)
    const float qscale = 0.08838834764831845f * 1.4426950408889634f;
    unsigned short* Tw = &As[wv * 1152];  // 16h x 72 per wave for V transpose
#pragma unroll
    for (int ni = 0; ni < 3; ++ni) {
        int f = 12 * nb + 3 * wv + ni;
        int col = f * 16 + l15;
        int h = col & 127;
        if (f < 16) {
            float bval = (f < 8) ? bq[h] : bk[h];
            unsigned short* dst = (f < 8) ? Qb : Kb;
#pragma unroll
            for (int mi = 0; mi < 4; ++mi)
#pragma unroll
                for (int r = 0; r < 4; ++r) {
                    int row = mbase + mi * 16 + quad * 4 + r;
                    float v = acc[mi][ni][r] + bval;
                    if (f < 8) v *= qscale;
                    dst[(long)row * HH + h] = f2bf(v);
                }
        } else {
            float bval = bv[h];
#pragma unroll
            for (int mi = 0; mi < 4; ++mi) {
                shortx4 pk;
#pragma unroll
                for (int r = 0; r < 4; ++r) pk[r] = (short)f2bf(acc[mi][ni][r] + bval);
                *(shortx4*)&Tw[l15 * 72 + mi * 16 + quad * 4] = pk;
            }
            int th = lane >> 2, seg = lane & 3;
            uintx4 q0 = *(const uintx4*)&Tw[th * 72 + seg * 16];
            uintx4 q1 = *(const uintx4*)&Tw[th * 72 + seg * 16 + 8];
            int hg = (f - 16) * 16 + th;
            int bb = mbase >> 12, t0 = (mbase & 4095) + seg * 16;
            unsigned short* vp = Vt + (long)bb * (HH * TT) + (long)hg * TT + t0;
            *(uintx4*)(vp) = q0;
            *(uintx4*)(vp + 8) = q1;
        }
    }
}

// ---------------- flash attention, causal, split-KV S=4, fixed-base softmax ----------------
// grid 2048 = 64 qb (descending) x 8 b x 4 s; block 256 (4 waves x 16 q-rows)
// p = exp2(s - MBASE): no online max, no rescale. Partials unnormalized + per-row l.
__global__ __launch_bounds__(256) void attn(
    const unsigned short* __restrict__ Qb, const unsigned short* __restrict__ Kb,
    const unsigned short* __restrict__ Vt, unsigned short* __restrict__ Op,
    float* __restrict__ Lh) {
    __shared__ unsigned short Ks[64 * 128];   // swizzled: slot(r,sc) holds chunk sc^(r&15)
    __shared__ unsigned short Vs[128 * 64];   // swizzled: slot(h,sc) holds chunk sc^(h&7)
    __shared__ unsigned short Ps[4 * 16 * 40];
    const int gid = blockIdx.x;
    const int qb = 63 - (gid >> 5);
    const int sub = gid & 31;
    const int b = sub & 7;
    const int s = sub >> 3;                   // 0..3
    const int len = qb + 1;
    const int lo = (s * len) >> 2;
    const int hi = ((s + 1) * len) >> 2;
    const int tid = threadIdx.x, lane = tid & 63, wv = tid >> 6;
    const int quad = lane >> 4, l15 = lane & 15;

    short8 qf[4];
    {
        const unsigned short* qp = Qb + ((long)b * TT + qb * 64 + wv * 16 + l15) * HH + quad * 8;
#pragma unroll
        for (int ks = 0; ks < 4; ++ks) qf[ks] = *(const short8*)(qp + ks * 32);
    }
    floatx4 o[8];
#pragma unroll
    for (int i = 0; i < 8; ++i) {
        floatx4 z = {0.f, 0.f, 0.f, 0.f};
        o[i] = z;
    }
    float l_part[4] = {0.f, 0.f, 0.f, 0.f};

    // staging addresses (loop-invariant components)
    const int kc = l15 ^ (4 * wv + quad);
    const unsigned short* Kg = Kb + (long)b * TT * HH + ((long)lo * 64 + 4 * wv + quad) * HH + kc * 8;
    const int vrow = lane >> 3;
    const int vc = (lane & 7) ^ (vrow & 7);
    const unsigned short* Vg = Vt + (long)b * HH * TT + (long)(8 * wv + vrow) * TT + lo * 64 + vc * 8;
    unsigned short* Pw = &Ps[wv * 640];

    for (int kb = lo; kb < hi; ++kb) {
#pragma unroll
        for (int h = 0; h < 4; ++h) {
            int grp = 4 * h + wv;
            async16(Kg + (long)h * (16 * HH), &Ks[grp * 512]);
            async16(Vg + (long)h * 32 * TT, &Vs[grp * 512]);
        }
        Kg += (long)64 * HH;
        Vg += 64;
        __syncthreads();

        floatx4 sArr[4];
#pragma unroll
        for (int nt = 0; nt < 4; ++nt) {
            floatx4 z = {0.f, 0.f, 0.f, 0.f};
            sArr[nt] = z;
        }
#pragma unroll
        for (int ks = 0; ks < 4; ++ks)
#pragma unroll
            for (int nt = 0; nt < 4; ++nt) {
                short8 kf = *(const short8*)&Ks[(nt * 16 + l15) * 128 + (((ks * 4 + quad) ^ l15) * 8)];
                sArr[nt] = __builtin_amdgcn_mfma_f32_16x16x32_bf16(qf[ks], kf, sArr[nt], 0, 0, 0);
            }

        if (kb == qb) {  // diagonal causal mask
            int rowl = wv * 16 + quad * 4;
#pragma unroll
            for (int nt = 0; nt < 4; ++nt) {
                int col = nt * 16 + l15;
#pragma unroll
                for (int r = 0; r < 4; ++r)
                    if (col > rowl + r) sArr[nt][r] = -1e30f;
            }
        }

        // fixed-base softmax: p = exp2(s - MBASE)
#pragma unroll
        for (int nt = 0; nt < 4; ++nt)
#pragma unroll
            for (int r = 0; r < 4; ++r)
                sArr[nt][r] = exp2f(sArr[nt][r] - MBASE);
#pragma unroll
        for (int r = 0; r < 4; ++r)
            l_part[r] += (sArr[0][r] + sArr[1][r]) + (sArr[2][r] + sArr[3][r]);

        // PV in two k2 halves through per-wave LDS (C-layout -> A-layout)
#pragma unroll
        for (int k2 = 0; k2 < 2; ++k2) {
#pragma unroll
            for (int ntl = 0; ntl < 2; ++ntl)
#pragma unroll
                for (int r = 0; r < 4; ++r)
                    Pw[(quad * 4 + r) * 40 + ntl * 16 + l15] = f2bf(sArr[k2 * 2 + ntl][r]);
            short8 pf = *(const short8*)&Pw[l15 * 40 + quad * 8];
#pragma unroll
            for (int hn = 0; hn < 8; ++hn) {
                short8 vf = *(const short8*)&Vs[(hn * 16 + l15) * 64 +
                                                (((k2 * 4 + quad) ^ (l15 & 7)) * 8)];
                o[hn] = __builtin_amdgcn_mfma_f32_16x16x32_bf16(pf, vf, o[hn], 0, 0, 0);
            }
        }
        __syncthreads();
    }

    long rbase = (long)b * TT + qb * 64 + wv * 16 + quad * 4;
    unsigned short* Os = Op + (long)s * BT * HH;
    if (hi > lo) {
#pragma unroll
        for (int hn = 0; hn < 8; ++hn)
#pragma unroll
            for (int r = 0; r < 4; ++r)
                Os[(rbase + r) * HH + hn * 16 + l15] = f2bf(o[hn][r]);
    }
    // reduce l across the 16 l15 lanes (row is fixed per (wv, quad, r))
#pragma unroll
    for (int r = 0; r < 4; ++r) {
        float l = l_part[r];
#pragma unroll
        for (int off = 1; off < 16; off <<= 1) l += __shfl_xor(l, off);
        if (l15 == 0) Lh[(long)s * BT + rbase + r] = (hi > lo) ? l : 0.f;
    }
}

// ---------------- merge the 4 KV-chunk partials: out = (sum o_s) / (sum l_s) ----------------
__global__ __launch_bounds__(256) void merge_kern(
    const unsigned short* __restrict__ Op, const float* __restrict__ Lh,
    float* __restrict__ out) {
    long e = ((long)blockIdx.x * 256 + threadIdx.x) * 8;
    long row = e >> 7;
    float lsum = Lh[row] + Lh[BT + row] + Lh[2 * (long)BT + row] + Lh[3 * (long)BT + row];
    float inv = 1.f / lsum;
    float acc[8];
#pragma unroll
    for (int j = 0; j < 8; ++j) acc[j] = 0.f;
#pragma unroll
    for (int s = 0; s < 4; ++s) {
        float ls = Lh[(long)s * BT + row];
        if (ls > 0.f) {
            uintx4 p = *(const uintx4*)(Op + (long)s * BT * HH + e);
#pragma unroll
            for (int j = 0; j < 4; ++j) {
                acc[2 * j]     += __uint_as_float(p[j] << 16);
                acc[2 * j + 1] += __uint_as_float(p[j] & 0xffff0000u);
            }
        }
    }
    floatx4 o0, o1;
#pragma unroll
    for (int j = 0; j < 4; ++j) {
        if (j < 2) { o0[2 * j] = acc[2 * j] * inv; o0[2 * j + 1] = acc[2 * j + 1] * inv; }
        else { o1[2 * (j - 2)] = acc[2 * j] * inv; o1[2 * (j - 2) + 1] = acc[2 * j + 1] * inv; }
    }
    *(floatx4*)(out + e) = o0;
    *(floatx4*)(out + e + 4) = o1;
}

extern "C" void kernel_launch(void* const* d_in, const int* in_sizes, int n_in,
                              void* d_out, int out_size, void* d_ws, size_t ws_size,
                              hipStream_t stream) {
    const float* x  = (const float*)d_in[0];
    const float* Wq = (const float*)d_in[1];
    const float* bq = (const float*)d_in[2];
    const float* Wk = (const float*)d_in[3];
    const float* bk = (const float*)d_in[4];
    const float* Wv = (const float*)d_in[5];
    const float* bv = (const float*)d_in[6];
    float* out = (float*)d_out;

    char* ws = (char*)d_ws;
    unsigned short* Wt = (unsigned short*)(ws);               // 786,432 B
    unsigned short* Qb = (unsigned short*)(ws + 1048576);     // pre-scaled by scale*log2e
    unsigned short* Kb = (unsigned short*)(ws + 9437184);
    unsigned short* Vt = (unsigned short*)(ws + 17825792);    // [B][H][T]
    unsigned short* Op = (unsigned short*)(ws + 26214400);    // 4 x 8,388,608 unnormalized partials
    float*          Lh = (float*)(ws + 59768832);             // 4 x 131,072 row sums
    // total ws use: 60,293,120 bytes

    conv_w<<<dim3(32, 4, 3), dim3(32, 8), 0, stream>>>(Wq, Wk, Wv, Wt);
    proj_gemm<<<dim3(2, 512), 256, 0, stream>>>(x, Wt, bq, bk, bv, Qb, Kb, Vt);
    attn<<<2048, 256, 0, stream>>>(Qb, Kb, Vt, Op, Lh);
    merge_kern<<<2048, 256, 0, stream>>>(Op, Lh, out);
}